// Round 7
// baseline (161.451 us; speedup 1.0000x reference)
//
#include <hip/hip_runtime.h>
#include <hip/hip_bf16.h>
#include <math.h>

#define T_LEN 2048
#define BATCH 4
#define DMODEL 256
#define MROWS (BATCH*T_LEN)
#define PLANE (MROWS*DMODEL)
#define CH_L 32
#define NCH  (T_LEN/CH_L)          // 64
#define SUMSZ (BATCH*NCH*DMODEL)   // 65536
#define MSLOT (DMODEL*DMODEL)      // 65536

typedef __bf16 bf16;
typedef __bf16 bf16x8 __attribute__((ext_vector_type(8)));
typedef float  f32x4  __attribute__((ext_vector_type(4)));
typedef unsigned short u16;
typedef u16 u16x8 __attribute__((ext_vector_type(8)));
typedef unsigned int u32;
typedef u32 u32x4 __attribute__((ext_vector_type(4)));

#define MFMA(a,b,c) __builtin_amdgcn_mfma_f32_16x16x32_bf16(a, b, c, 0, 0, 0)

__device__ __forceinline__ void split_bf16(float x, bf16& hi, bf16& lo) {
    hi = (bf16)x;
    lo = (bf16)(x - (float)hi);
}

__device__ __forceinline__ float pack_split_f(float x) {
    bf16 h, l; split_bf16(x, h, l);
    union { bf16 b; u16 u; } a, b2; a.b = h; b2.b = l;
    u32 v = (u32)a.u | ((u32)b2.u << 16);
    return __builtin_bit_cast(float, v);
}

__device__ __forceinline__ float bflo(u32 v) { union { u16 u; bf16 b; } c; c.u = (u16)(v & 0xffffu); return (float)c.b; }
__device__ __forceinline__ float bfhi(u32 v) { union { u16 u; bf16 b; } c; c.u = (u16)(v >> 16); return (float)c.b; }

__device__ __forceinline__ void split8(const float* p, bf16x8& h, bf16x8& l) {
    f32x4 a = *(const f32x4*)p;
    f32x4 b = *(const f32x4*)(p + 4);
    #pragma unroll
    for (int e = 0; e < 4; ++e) {
        bf16 hh, ll;
        split_bf16(a[e], hh, ll); h[e] = hh; l[e] = ll;
        split_bf16(b[e], hh, ll); h[4+e] = hh; l[4+e] = ll;
    }
}

// fast transcendentals (hardware v_exp_f32 based)
__device__ __forceinline__ float tanh_fast(float z) {
    z = fminf(fmaxf(z, -15.f), 15.f);
    float e = __expf(2.f * z);
    return (e - 1.f) / (e + 1.f);
}
__device__ __forceinline__ float nsoftplus_fast(float y) {   // -softplus(y)
    return -(fmaxf(y, 0.f) + __logf(1.f + __expf(-fabsf(y))));
}
__device__ __forceinline__ float sigmoid_fast(float y) {
    return 1.f / (1.f + __expf(-y));
}

#define GLD16(SRC, DST) __builtin_amdgcn_global_load_lds( \
    (const __attribute__((address_space(1))) void*)(SRC), \
    (__attribute__((address_space(3))) void*)(DST), 16, 0, 0)

// ---------------- split x into bf16 hi/lo planes (grid = PLANE/2048 = 1024)
__global__ __launch_bounds__(256) void split_x(const float* __restrict__ x,
                                               bf16* __restrict__ xh,
                                               bf16* __restrict__ xl) {
    int i = (blockIdx.x*256 + threadIdx.x) * 8;
    f32x4 a = *(const f32x4*)(x + i);
    f32x4 b = *(const f32x4*)(x + i + 4);
    bf16x8 h, l;
    #pragma unroll
    for (int e = 0; e < 4; ++e) {
        bf16 hh, ll;
        split_bf16(a[e], hh, ll); h[e] = hh;   l[e] = ll;
        split_bf16(b[e], hh, ll); h[4+e] = hh; l[4+e] = ll;
    }
    *(bf16x8*)(xh + i) = h;
    *(bf16x8*)(xl + i) = l;
}

// ---------------- pack weights (coalesced LDS transpose): WcatT[n][k] hi/lo, n in [0,1536)
__global__ __launch_bounds__(256) void pack_w(const float* __restrict__ Wq,
                                              const float* __restrict__ Wk,
                                              const float* __restrict__ Wv,
                                              const float* __restrict__ Wg,
                                              bf16* __restrict__ WhT,
                                              bf16* __restrict__ WlT) {
    __shared__ float tile[16][260];   // [n-local][k]
    const int tid = threadIdx.x;
    const int n0 = blockIdx.x * 16;
    const float* src; int nb, nw;
    if (n0 < 256)      { src = Wq; nb = n0;       nw = 256; }
    else if (n0 < 512) { src = Wk; nb = n0 - 256; nw = 256; }
    else if (n0 < 768) { src = Wv; nb = n0 - 512; nw = 256; }
    else               { src = Wg; nb = n0 - 768; nw = 768; }
    const int j = tid & 15, kk = tid >> 4;
    #pragma unroll
    for (int r = 0; r < 16; ++r) {
        int k = r*16 + kk;
        tile[j][k] = src[(size_t)k*nw + nb + j];
    }
    __syncthreads();
    #pragma unroll
    for (int r = 0; r < 16; ++r) {
        float v = tile[r][tid];
        bf16 h, l; split_bf16(v, h, l);
        WhT[(size_t)(n0 + r)*256 + tid] = h;
        WlT[(size_t)(n0 + r)*256 + tid] = l;
    }
}

// ---------------- fused projection GEMM: NO LDS, no barriers, no per-elem VALU.
// A and B fragments load directly as bf16x8 dwordx4 from pre-split planes.
// Per K-step: 16 independent loads -> 48 MFMA. [8192,256] x [256,1536].
__global__ __launch_bounds__(256, 3) void proj_gemm(
    const bf16* __restrict__ xh, const bf16* __restrict__ xl,
    const bf16* __restrict__ WhT, const bf16* __restrict__ WlT,
    const float* __restrict__ bq, const float* __restrict__ bk, const float* __restrict__ bv,
    const float* __restrict__ bg, const float* __restrict__ input_bias,
    float* __restrict__ qP, float* __restrict__ kP, float* __restrict__ vP,
    float* __restrict__ liP, float* __restrict__ lfP, float* __restrict__ soP)
{
    const int tid = threadIdx.x;
    const int w = tid >> 6, l = tid & 63;
    const int wr = w >> 1, wc = w & 1;
    const int m0 = blockIdx.x * 128;
    const int n0 = blockIdx.y * 128;
    const int lr = l & 15, lk = l >> 4;

    const bf16 *ahp[4], *alp[4], *bhp[4], *blp[4];
    #pragma unroll
    for (int mi = 0; mi < 4; ++mi) {
        size_t ro = (size_t)(m0 + wr*64 + mi*16 + lr)*256 + lk*8;
        ahp[mi] = xh + ro; alp[mi] = xl + ro;
    }
    #pragma unroll
    for (int ni = 0; ni < 4; ++ni) {
        size_t co = (size_t)(n0 + wc*64 + ni*16 + lr)*256 + lk*8;
        bhp[ni] = WhT + co; blp[ni] = WlT + co;
    }

    f32x4 acc[4][4] = {};

    #pragma unroll
    for (int ki = 0; ki < 8; ++ki) {
        const int off = ki*32;
        bf16x8 afh[4], afl[4], bfh[4], bfl[4];
        #pragma unroll
        for (int mi = 0; mi < 4; ++mi) {
            afh[mi] = *(const bf16x8*)(ahp[mi] + off);
            afl[mi] = *(const bf16x8*)(alp[mi] + off);
        }
        #pragma unroll
        for (int ni = 0; ni < 4; ++ni) {
            bfh[ni] = *(const bf16x8*)(bhp[ni] + off);
            bfl[ni] = *(const bf16x8*)(blp[ni] + off);
        }
        #pragma unroll
        for (int ni = 0; ni < 4; ++ni)
            #pragma unroll
            for (int mi = 0; mi < 4; ++mi) {
                acc[mi][ni] = MFMA(afh[mi], bfh[ni], acc[mi][ni]);
                acc[mi][ni] = MFMA(afl[mi], bfh[ni], acc[mi][ni]);
                acc[mi][ni] = MFMA(afh[mi], bfl[ni], acc[mi][ni]);
            }
    }

    const int seg = n0 >> 8;   // 0=q 1=k 2=v 3=i 4=f 5=o (uniform per wg)
    #pragma unroll
    for (int mi = 0; mi < 4; ++mi) {
        #pragma unroll
        for (int ni = 0; ni < 4; ++ni) {
            int gcol = n0 + wc*64 + ni*16 + lr;
            int c = gcol & 255;
            #pragma unroll
            for (int r = 0; r < 4; ++r) {
                int grow = m0 + wr*64 + mi*16 + lk*4 + r;
                float val = acc[mi][ni][r];
                size_t o = (size_t)grow*256 + c;
                if (seg == 0)      qP[o] = val + bq[c];
                else if (seg == 1) kP[o] = (val + bk[c]) * 0.0625f;
                else if (seg == 2) vP[o] = val + bv[c];
                else if (seg == 3) { float y = val + bg[c] + input_bias[c];
                                     liP[o] = 10.0f * tanh_fast(y * 0.1f); }
                else if (seg == 4) { float y = val + bg[256 + c];
                                     lfP[o] = nsoftplus_fast(y); }
                else               { float y = val + bg[512 + c];
                                     soP[o] = sigmoid_fast(y); }
            }
        }
    }
}

// ---------------- chunk summaries: per (b,c,j): C = sum lf; mu = max(li - Cpref); Bn
__global__ __launch_bounds__(256) void chunk_summary(
    const float* __restrict__ lfP, const float* __restrict__ liP, const float* __restrict__ kP,
    float* __restrict__ Csum, float* __restrict__ Mu, float* __restrict__ Bn)
{
    const int b = blockIdx.x >> 6, c = blockIdx.x & 63;
    const int j = threadIdx.x;
    const size_t base = ((size_t)b*T_LEN + (size_t)c*CH_L)*DMODEL + j;
    float C = 0.f, mu = -3e38f;
    float val[CH_L];
    #pragma unroll
    for (int s = 0; s < CH_L; ++s) {
        C += lfP[base + (size_t)s*DMODEL];
        val[s] = liP[base + (size_t)s*DMODEL] - C;
        mu = fmaxf(mu, val[s]);
    }
    float bn = 0.f;
    #pragma unroll
    for (int s = 0; s < CH_L; ++s)
        bn += __expf(val[s] - mu) * kP[base + (size_t)s*DMODEL];
    size_t o = ((size_t)b*NCH + c)*DMODEL + j;
    Csum[o] = C; Mu[o] = mu; Bn[o] = bn;
}

// ---------------- sequential compose of (m,n) boundary states across 64 chunks (tiny)
__global__ __launch_bounds__(256) void chunk_compose(
    const float* __restrict__ Csum, const float* __restrict__ Mu, const float* __restrict__ Bn,
    float* __restrict__ mIn, float* __restrict__ nIn, float* __restrict__ Th,
    float* __restrict__ Dd)
{
    const int b = blockIdx.x;
    const int j = threadIdx.x;
    float m = 0.f, n = 0.f;
    for (int c = 0; c < NCH; ++c) {
        size_t o = ((size_t)b*NCH + c)*DMODEL + j;
        mIn[o] = m; nIn[o] = n;
        float cs = Csum[o], mu = Mu[o], bn = Bn[o];
        float th = fmaxf(m, mu);
        Th[o] = th;
        float d = __expf(m - th);
        Dd[o] = d;
        n = d*n + __expf(mu - th)*bn;
        m = cs + th;
    }
}

// ---------------- Delta-M per chunk: DM[b,c] = Bhat^T K  (256x256, MFMA)
__global__ __launch_bounds__(256) void s2_dm(
    const float* __restrict__ kP, const float* __restrict__ vP,
    const float* __restrict__ liP, const float* __restrict__ lfP,
    const float* __restrict__ Th, float* __restrict__ DM)
{
    __shared__ bf16 BTh[DMODEL][40], BTl[DMODEL][40];
    __shared__ bf16 KTh[DMODEL][40], KTl[DMODEL][40];
    const int tid = threadIdx.x;
    const int w = tid >> 6, l = tid & 63;
    const int b = blockIdx.x >> 6, c = blockIdx.x & 63;
    const size_t pb = ((size_t)b*T_LEN + (size_t)c*CH_L)*DMODEL;

    {
        const float thL = Th[((size_t)b*NCH + c)*DMODEL + tid];
        float C = 0.f;
        #pragma unroll
        for (int s = 0; s < CH_L; ++s) {
            size_t o = pb + (size_t)s*DMODEL + tid;
            float lf = lfP[o], li = liP[o], vv = vP[o], kv = kP[o];
            C += lf;
            float bv = __expf(li - C - thL) * vv;
            bf16 h, lo; split_bf16(bv, h, lo);
            BTh[tid][s] = h; BTl[tid][s] = lo;
            bf16 kh, kl; split_bf16(kv, kh, kl);
            KTh[tid][s] = kh; KTl[tid][s] = kl;
        }
    }
    __syncthreads();

    const int lr = l & 15, lk = l >> 4;
    bf16x8 Ah[4], Al[4];
    #pragma unroll
    for (int it = 0; it < 4; ++it) {
        int row = w*64 + it*16 + lr;
        Ah[it] = *(const bf16x8*)&BTh[row][lk*8];
        Al[it] = *(const bf16x8*)&BTl[row][lk*8];
    }
    float* DMc = DM + (size_t)((size_t)b*NCH + c)*MSLOT;
    #pragma unroll
    for (int jt = 0; jt < 16; ++jt) {
        int jcol = jt*16 + lr;
        bf16x8 bh = *(const bf16x8*)&KTh[jcol][lk*8];
        bf16x8 bl = *(const bf16x8*)&KTl[jcol][lk*8];
        #pragma unroll
        for (int it = 0; it < 4; ++it) {
            f32x4 a = {0.f,0.f,0.f,0.f};
            a = MFMA(Ah[it], bh, a);
            a = MFMA(Al[it], bh, a);
            a = MFMA(Ah[it], bl, a);
            #pragma unroll
            for (int r = 0; r < 4; ++r)
                DMc[(size_t)(w*64 + it*16 + lk*4 + r)*DMODEL + jcol] = a[r];
        }
    }
}

// ---------------- compose M across chunks per (b,i,j); write boundary states packed-split in-place
__global__ __launch_bounds__(256) void s3_compose(
    const float* __restrict__ Dd, float* __restrict__ DM)
{
    const int b = blockIdx.x >> 8, i = blockIdx.x & 255;
    const int j = threadIdx.x;
    float acc = 0.f;
    const size_t base = ((size_t)b*NCH)*MSLOT + (size_t)i*DMODEL + j;
    for (int c = 0; c < NCH; ++c) {
        size_t a = base + (size_t)c*MSLOT;
        float dm = DM[a];
        if (c > 0) DM[a] = pack_split_f(acc);
        float d = Dd[((size_t)b*NCH + c)*DMODEL + i];
        acc = d*acc + dm;
    }
}

// ---------------- per-chunk output + fused RMSNorm:
// H = F1*(Q Mprev^T) + Bt*(Gm^T Bhat); h = sigma(o)*H/denom; out = h/rms * scale
__global__ __launch_bounds__(256) void s4_chunk(
    const float* __restrict__ qP, const float* __restrict__ kP, const float* __restrict__ vP,
    const float* __restrict__ liP, const float* __restrict__ lfP, const float* __restrict__ soP,
    const float* __restrict__ mIn, const float* __restrict__ nIn, const float* __restrict__ Th,
    const float* __restrict__ DM, const float* __restrict__ norm_scale,
    float* __restrict__ out)
{
    __shared__ float Kf[CH_L][268];
    __shared__ float Qf[CH_L][268];       // aliased as Hout in the epilogue
    __shared__ float Pbuf[CH_L][260];     // aliased as packed scales
    __shared__ bf16 BTh[DMODEL][40];
    __shared__ float GT[CH_L][44];
    __shared__ float denoms[CH_L];

    const int tid = threadIdx.x;
    const int w = tid >> 6, l = tid & 63;
    const int b = blockIdx.x >> 6;
    const int c = blockIdx.x & 63;
    const size_t pb = ((size_t)b*T_LEN + (size_t)c*CH_L)*DMODEL;

    // phase 0: stage K,Q fp32 rows into LDS (completes under phase 1)
    #pragma unroll
    for (int r8 = 0; r8 < 8; ++r8) {
        int row = w*8 + r8;
        GLD16(kP + pb + (size_t)row*DMODEL + l*4, &Kf[row][l*4]);
        GLD16(qP + pb + (size_t)row*DMODEL + l*4, &Qf[row][l*4]);
    }

    // phase 1: per-dim recurrences (thread = dim)
    const int i = tid;
    const size_t cbx = ((size_t)b*NCH + c)*DMODEL + i;
    const float thL = Th[cbx];
    const float mI = mIn[cbx];
    float th_arr[CH_L];
    {
        float C = 0.f, mu = -3e38f, n = nIn[cbx], thp = mI;
        #pragma unroll
        for (int t = 0; t < CH_L; ++t) {
            size_t o = pb + (size_t)t*DMODEL + i;
            float lf = lfP[o], li = liP[o], kv = kP[o], qv = qP[o], vv = vP[o];
            C += lf;
            float vlc = li - C;
            mu = fmaxf(mu, vlc);
            float tht = fmaxf(mI, mu);
            th_arr[t] = tht;
            float f = __expf(thp - tht);
            float iv = __expf(vlc - tht);
            n = f*n + iv*kv;
            thp = tht;
            Pbuf[t][i] = n * qv;
            BTh[i][t] = (bf16)(__expf(vlc - thL) * vv);
        }
    }
    __syncthreads();

    // phase 2: denominators
    #pragma unroll
    for (int r = 0; r < 8; ++r) {
        int t = w*8 + r;
        f32x4 pv = *(const f32x4*)&Pbuf[t][l*4];
        float s = pv[0]+pv[1]+pv[2]+pv[3];
        #pragma unroll
        for (int sh = 32; sh; sh >>= 1) s += __shfl_xor(s, sh);
        if (l == 0) denoms[t] = fmaxf(fabsf(s), 1e-6f);
    }
    __syncthreads();

    // phase 3a: packed scales (F1, Bt) -> alias over Pbuf
    u32 (*scl)[260] = (u32(*)[260])Pbuf;
    #pragma unroll
    for (int t = 0; t < CH_L; ++t) {
        float F1 = __expf(mI - th_arr[t]);
        float Bt = __expf(thL - th_arr[t]);
        union { bf16 b; u16 u; } a1, a2; a1.b = (bf16)F1; a2.b = (bf16)Bt;
        scl[t][i] = (u32)a1.u | ((u32)a2.u << 16);
    }
    // phase 3b: G = K Q^T, one 16x16 tile per wave, masked write transposed
    {
        const int srow = (w & 1)*16, tcol = (w >> 1)*16;
        const int lr = l & 15, lk2 = l >> 4;
        f32x4 g = {0.f,0.f,0.f,0.f};
        #pragma unroll
        for (int ks = 0; ks < 8; ++ks) {
            bf16x8 ah, al, bh, bl;
            split8(&Kf[srow + lr][ks*32 + lk2*8], ah, al);
            split8(&Qf[tcol + lr][ks*32 + lk2*8], bh, bl);
            g = MFMA(ah, bh, g);
            g = MFMA(al, bh, g);
            g = MFMA(ah, bl, g);
        }
        #pragma unroll
        for (int r = 0; r < 4; ++r) {
            int s = srow + lk2*4 + r, t = tcol + lr;
            GT[t][s] = (s <= t) ? g[r] : 0.f;
        }
    }
    __syncthreads();

    // phase 4: output GEMMs. wave -> (t-half tt, 8 i-tiles)
    const int tt = w & 1;
    const int lr = l & 15, lk2 = l >> 4;
    const int trow = tt*16 + lr;
    f32x4 acc_a[8], acc_b[8];

    {   // intra: Gm^T Bhat  (K-dim = 32 = chunk)
        bf16x8 gh, gl;
        split8(&GT[trow][lk2*8], gh, gl);
        #pragma unroll
        for (int it = 0; it < 8; ++it) {
            int irow = ((w>>1)*8 + it)*16 + lr;
            bf16x8 bb = *(const bf16x8*)&BTh[irow][lk2*8];
            f32x4 a = {0.f,0.f,0.f,0.f};
            a = MFMA(gh, bb, a);
            a = MFMA(gl, bb, a);
            acc_a[it] = a;
        }
    }
    #pragma unroll
    for (int it = 0; it < 8; ++it) acc_b[it] = (f32x4){0.f,0.f,0.f,0.f};
    if (c > 0) {   // inter: Q Mprev^T, Mprev streamed packed-split from global
        const u32* Mbase = (const u32*)DM + (size_t)((size_t)b*NCH + c)*MSLOT;
        #pragma unroll
        for (int ks = 0; ks < 8; ++ks) {
            bf16x8 qh, ql;
            split8(&Qf[trow][ks*32 + lk2*8], qh, ql);
            #pragma unroll
            for (int it = 0; it < 8; ++it) {
                int irow = ((w>>1)*8 + it)*16 + lr;
                const u32* mp = Mbase + (size_t)irow*DMODEL + ks*32 + lk2*8;
                u32x4 ma = *(const u32x4*)mp;
                u32x4 mb = *(const u32x4*)(mp + 4);
                union { u16x8 u; bf16x8 h; } Mh, Ml;
                #pragma unroll
                for (int e = 0; e < 4; ++e) {
                    Mh.u[e]   = (u16)(ma[e] & 0xffffu); Ml.u[e]   = (u16)(ma[e] >> 16);
                    Mh.u[4+e] = (u16)(mb[e] & 0xffffu); Ml.u[4+e] = (u16)(mb[e] >> 16);
                }
                f32x4 a = acc_b[it];
                a = MFMA(qh, Mh.h, a);
                a = MFMA(ql, Mh.h, a);
                a = MFMA(qh, Ml.h, a);
                acc_b[it] = a;
            }
        }
    }
    // epilogue part 1: combine into pre-norm h, park in LDS (alias Qf after all reads done)
    __syncthreads();
    float* Hout = &Qf[0][0];             // [32][268]
    #pragma unroll
    for (int it = 0; it < 8; ++it) {
        int icol = ((w>>1)*8 + it)*16 + lr;
        #pragma unroll
        for (int r = 0; r < 4; ++r) {
            int t = tt*16 + lk2*4 + r;
            u32 sc = scl[t][icol];
            float h = bflo(sc)*acc_b[it][r] + bfhi(sc)*acc_a[it][r];
            size_t o = pb + (size_t)t*DMODEL + icol;
            Hout[t*268 + icol] = soP[o] * h / denoms[t];
        }
    }
    __syncthreads();
    // epilogue part 2: fused RMSNorm (wave w owns rows w*8..w*8+7), coalesced stores
    #pragma unroll
    for (int r = 0; r < 8; ++r) {
        int t = w*8 + r;
        f32x4 hv = *(const f32x4*)&Hout[t*268 + l*4];
        float ss = hv[0]*hv[0] + hv[1]*hv[1] + hv[2]*hv[2] + hv[3]*hv[3];
        #pragma unroll
        for (int sh = 32; sh; sh >>= 1) ss += __shfl_xor(ss, sh);
        float rinv = rsqrtf(ss * (1.0f/256.0f) + 1e-8f);
        f32x4 ns = *(const f32x4*)(norm_scale + l*4);
        f32x4 o4;
        #pragma unroll
        for (int e = 0; e < 4; ++e) o4[e] = hv[e] * rinv * ns[e];
        *(f32x4*)(out + pb + (size_t)t*DMODEL + l*4) = o4;
    }
}

extern "C" void kernel_launch(void* const* d_in, const int* in_sizes, int n_in,
                              void* d_out, int out_size, void* d_ws, size_t ws_size,
                              hipStream_t stream) {
    const float* x          = (const float*)d_in[0];
    const float* Wq         = (const float*)d_in[1];
    const float* bq         = (const float*)d_in[2];
    const float* Wk         = (const float*)d_in[3];
    const float* bk         = (const float*)d_in[4];
    const float* Wv         = (const float*)d_in[5];
    const float* bv         = (const float*)d_in[6];
    const float* Wg         = (const float*)d_in[7];
    const float* bg         = (const float*)d_in[8];
    const float* input_bias = (const float*)d_in[9];
    const float* norm_scale = (const float*)d_in[10];
    float* out = (float*)d_out;

    float* qP   = (float*)d_ws;
    float* kP   = qP  + PLANE;
    float* vP   = kP  + PLANE;
    float* liP  = vP  + PLANE;
    float* lfP  = liP + PLANE;
    float* soP  = lfP + PLANE;
    float* Csum = soP + PLANE;
    float* Mu   = Csum + SUMSZ;
    float* Bn   = Mu   + SUMSZ;
    float* mIn  = Bn   + SUMSZ;
    float* nIn  = mIn  + SUMSZ;
    float* Th   = nIn  + SUMSZ;
    float* Dd   = Th   + SUMSZ;
    float* DM   = Dd   + SUMSZ;                       // 4*64*65536 floats = 64 MiB
    bf16*  WhT  = (bf16*)(DM + (size_t)BATCH*NCH*MSLOT);
    bf16*  WlT  = WhT + 1536*256;
    bf16*  xh   = WlT + 1536*256;
    bf16*  xl   = xh + PLANE;

    pack_w<<<dim3(96), dim3(256), 0, stream>>>(Wq, Wk, Wv, Wg, WhT, WlT);
    split_x<<<dim3(1024), dim3(256), 0, stream>>>(x, xh, xl);
    proj_gemm<<<dim3(64, 12), dim3(256), 0, stream>>>(xh, xl, WhT, WlT, bq, bk, bv, bg, input_bias,
                                                      qP, kP, vP, liP, lfP, soP);
    chunk_summary<<<dim3(BATCH*NCH), dim3(256), 0, stream>>>(lfP, liP, kP, Csum, Mu, Bn);
    chunk_compose<<<dim3(BATCH), dim3(256), 0, stream>>>(Csum, Mu, Bn, mIn, nIn, Th, Dd);
    s2_dm<<<dim3(BATCH*NCH), dim3(256), 0, stream>>>(kP, vP, liP, lfP, Th, DM);
    s3_compose<<<dim3(BATCH*256), dim3(256), 0, stream>>>(Dd, DM);
    s4_chunk<<<dim3(BATCH*NCH), dim3(256), 0, stream>>>(qP, kP, vP, liP, lfP, soP,
                                                        mIn, nIn, Th, DM, norm_scale, out);
}

// Round 8
// 143.073 us; speedup vs baseline: 1.1285x; 1.1285x over previous
//
#include <hip/hip_runtime.h>
#include <hip/hip_bf16.h>
#include <math.h>

#define T_LEN 2048
#define BATCH 4
#define DMODEL 256
#define MROWS (BATCH*T_LEN)
#define PLANE (MROWS*DMODEL)
#define CH_L 32
#define NCH  (T_LEN/CH_L)          // 64
#define SUMSZ (BATCH*NCH*DMODEL)   // 65536
#define MSLOT (DMODEL*DMODEL)      // 65536

typedef __bf16 bf16;
typedef __bf16 bf16x8 __attribute__((ext_vector_type(8)));
typedef float  f32x4  __attribute__((ext_vector_type(4)));
typedef unsigned short u16;
typedef u16 u16x8 __attribute__((ext_vector_type(8)));
typedef unsigned int u32;
typedef u32 u32x4 __attribute__((ext_vector_type(4)));

#define MFMA(a,b,c) __builtin_amdgcn_mfma_f32_16x16x32_bf16(a, b, c, 0, 0, 0)

__device__ __forceinline__ void split_bf16(float x, bf16& hi, bf16& lo) {
    hi = (bf16)x;
    lo = (bf16)(x - (float)hi);
}

__device__ __forceinline__ float bflo(u32 v) { union { u16 u; bf16 b; } c; c.u = (u16)(v & 0xffffu); return (float)c.b; }
__device__ __forceinline__ float bfhi(u32 v) { union { u16 u; bf16 b; } c; c.u = (u16)(v >> 16); return (float)c.b; }

__device__ __forceinline__ void split8(const float* p, bf16x8& h, bf16x8& l) {
    f32x4 a = *(const f32x4*)p;
    f32x4 b = *(const f32x4*)(p + 4);
    #pragma unroll
    for (int e = 0; e < 4; ++e) {
        bf16 hh, ll;
        split_bf16(a[e], hh, ll); h[e] = hh; l[e] = ll;
        split_bf16(b[e], hh, ll); h[4+e] = hh; l[4+e] = ll;
    }
}

// fast transcendentals (hardware v_exp_f32 based)
__device__ __forceinline__ float tanh_fast(float z) {
    z = fminf(fmaxf(z, -15.f), 15.f);
    float e = __expf(2.f * z);
    return (e - 1.f) / (e + 1.f);
}
__device__ __forceinline__ float nsoftplus_fast(float y) {   // -softplus(y)
    return -(fmaxf(y, 0.f) + __logf(1.f + __expf(-fabsf(y))));
}
__device__ __forceinline__ float sigmoid_fast(float y) {
    return 1.f / (1.f + __expf(-y));
}

#define GLD16(SRC, DST) __builtin_amdgcn_global_load_lds( \
    (const __attribute__((address_space(1))) void*)(SRC), \
    (__attribute__((address_space(3))) void*)(DST), 16, 0, 0)

// ---------------- split x into bf16 hi/lo planes (grid = PLANE/2048 = 1024)
__global__ __launch_bounds__(256) void split_x(const float* __restrict__ x,
                                               bf16* __restrict__ xh,
                                               bf16* __restrict__ xl) {
    int i = (blockIdx.x*256 + threadIdx.x) * 8;
    f32x4 a = *(const f32x4*)(x + i);
    f32x4 b = *(const f32x4*)(x + i + 4);
    bf16x8 h, l;
    #pragma unroll
    for (int e = 0; e < 4; ++e) {
        bf16 hh, ll;
        split_bf16(a[e], hh, ll); h[e] = hh;   l[e] = ll;
        split_bf16(b[e], hh, ll); h[4+e] = hh; l[4+e] = ll;
    }
    *(bf16x8*)(xh + i) = h;
    *(bf16x8*)(xl + i) = l;
}

// ---------------- pack weights (coalesced LDS transpose): WcatT[n][k] hi/lo, n in [0,1536)
__global__ __launch_bounds__(256) void pack_w(const float* __restrict__ Wq,
                                              const float* __restrict__ Wk,
                                              const float* __restrict__ Wv,
                                              const float* __restrict__ Wg,
                                              bf16* __restrict__ WhT,
                                              bf16* __restrict__ WlT) {
    __shared__ float tile[16][260];   // [n-local][k]
    const int tid = threadIdx.x;
    const int n0 = blockIdx.x * 16;
    const float* src; int nb, nw;
    if (n0 < 256)      { src = Wq; nb = n0;       nw = 256; }
    else if (n0 < 512) { src = Wk; nb = n0 - 256; nw = 256; }
    else if (n0 < 768) { src = Wv; nb = n0 - 512; nw = 256; }
    else               { src = Wg; nb = n0 - 768; nw = 768; }
    const int j = tid & 15, kk = tid >> 4;
    #pragma unroll
    for (int r = 0; r < 16; ++r) {
        int k = r*16 + kk;
        tile[j][k] = src[(size_t)k*nw + nb + j];
    }
    __syncthreads();
    #pragma unroll
    for (int r = 0; r < 16; ++r) {
        float v = tile[r][tid];
        bf16 h, l; split_bf16(v, h, l);
        WhT[(size_t)(n0 + r)*256 + tid] = h;
        WlT[(size_t)(n0 + r)*256 + tid] = l;
    }
}

// ---------------- fused projection GEMM: no LDS/barriers; explicit register
// double-buffer — load next K-step's 16 fragments while MFMAing current.
// [8192,256] x [256,1536], per-segment fast-math epilogue.
__global__ __launch_bounds__(256, 2) void proj_gemm(
    const bf16* __restrict__ xh, const bf16* __restrict__ xl,
    const bf16* __restrict__ WhT, const bf16* __restrict__ WlT,
    const float* __restrict__ bq, const float* __restrict__ bk, const float* __restrict__ bv,
    const float* __restrict__ bg, const float* __restrict__ input_bias,
    float* __restrict__ qP, float* __restrict__ kP, float* __restrict__ vP,
    float* __restrict__ liP, float* __restrict__ lfP, float* __restrict__ soP)
{
    const int tid = threadIdx.x;
    const int w = tid >> 6, l = tid & 63;
    const int wr = w >> 1, wc = w & 1;
    const int m0 = blockIdx.x * 128;
    const int n0 = blockIdx.y * 128;
    const int lr = l & 15, lk = l >> 4;

    const bf16 *ahp[4], *alp[4], *bhp[4], *blp[4];
    #pragma unroll
    for (int mi = 0; mi < 4; ++mi) {
        size_t ro = (size_t)(m0 + wr*64 + mi*16 + lr)*256 + lk*8;
        ahp[mi] = xh + ro; alp[mi] = xl + ro;
    }
    #pragma unroll
    for (int ni = 0; ni < 4; ++ni) {
        size_t co = (size_t)(n0 + wc*64 + ni*16 + lr)*256 + lk*8;
        bhp[ni] = WhT + co; blp[ni] = WlT + co;
    }

    f32x4 acc[4][4] = {};
    bf16x8 a0h[4], a0l[4], b0h[4], b0l[4];
    bf16x8 a1h[4], a1l[4], b1h[4], b1l[4];

    #define LOADF(AH, AL, BH, BL, OFF) { \
        _Pragma("unroll") \
        for (int mi = 0; mi < 4; ++mi) { \
            AH[mi] = *(const bf16x8*)(ahp[mi] + (OFF)); \
            AL[mi] = *(const bf16x8*)(alp[mi] + (OFF)); } \
        _Pragma("unroll") \
        for (int ni = 0; ni < 4; ++ni) { \
            BH[ni] = *(const bf16x8*)(bhp[ni] + (OFF)); \
            BL[ni] = *(const bf16x8*)(blp[ni] + (OFF)); } }

    #define MFMAS(AH, AL, BH, BL) { \
        _Pragma("unroll") \
        for (int ni = 0; ni < 4; ++ni) \
            _Pragma("unroll") \
            for (int mi = 0; mi < 4; ++mi) { \
                acc[mi][ni] = MFMA(AH[mi], BH[ni], acc[mi][ni]); \
                acc[mi][ni] = MFMA(AL[mi], BH[ni], acc[mi][ni]); \
                acc[mi][ni] = MFMA(AH[mi], BL[ni], acc[mi][ni]); } }

    LOADF(a0h, a0l, b0h, b0l, 0)
    #pragma unroll
    for (int kk = 0; kk < 4; ++kk) {
        LOADF(a1h, a1l, b1h, b1l, kk*64 + 32)
        MFMAS(a0h, a0l, b0h, b0l)
        if (kk < 3) LOADF(a0h, a0l, b0h, b0l, kk*64 + 64)
        MFMAS(a1h, a1l, b1h, b1l)
    }
    #undef LOADF
    #undef MFMAS

    const int seg = n0 >> 8;   // 0=q 1=k 2=v 3=i 4=f 5=o (uniform per wg)
    #pragma unroll
    for (int mi = 0; mi < 4; ++mi) {
        #pragma unroll
        for (int ni = 0; ni < 4; ++ni) {
            int gcol = n0 + wc*64 + ni*16 + lr;
            int c = gcol & 255;
            #pragma unroll
            for (int r = 0; r < 4; ++r) {
                int grow = m0 + wr*64 + mi*16 + lk*4 + r;
                float val = acc[mi][ni][r];
                size_t o = (size_t)grow*256 + c;
                if (seg == 0)      qP[o] = val + bq[c];
                else if (seg == 1) kP[o] = (val + bk[c]) * 0.0625f;
                else if (seg == 2) vP[o] = val + bv[c];
                else if (seg == 3) { float y = val + bg[c] + input_bias[c];
                                     liP[o] = 10.0f * tanh_fast(y * 0.1f); }
                else if (seg == 4) { float y = val + bg[256 + c];
                                     lfP[o] = nsoftplus_fast(y); }
                else               { float y = val + bg[512 + c];
                                     soP[o] = sigmoid_fast(y); }
            }
        }
    }
}

// ---------------- chunk summaries: per (b,c,j): C = sum lf; mu = max(li - Cpref); Bn
__global__ __launch_bounds__(256) void chunk_summary(
    const float* __restrict__ lfP, const float* __restrict__ liP, const float* __restrict__ kP,
    float* __restrict__ Csum, float* __restrict__ Mu, float* __restrict__ Bn)
{
    const int b = blockIdx.x >> 6, c = blockIdx.x & 63;
    const int j = threadIdx.x;
    const size_t base = ((size_t)b*T_LEN + (size_t)c*CH_L)*DMODEL + j;
    float C = 0.f, mu = -3e38f;
    float val[CH_L];
    #pragma unroll
    for (int s = 0; s < CH_L; ++s) {
        C += lfP[base + (size_t)s*DMODEL];
        val[s] = liP[base + (size_t)s*DMODEL] - C;
        mu = fmaxf(mu, val[s]);
    }
    float bn = 0.f;
    #pragma unroll
    for (int s = 0; s < CH_L; ++s)
        bn += __expf(val[s] - mu) * kP[base + (size_t)s*DMODEL];
    size_t o = ((size_t)b*NCH + c)*DMODEL + j;
    Csum[o] = C; Mu[o] = mu; Bn[o] = bn;
}

// ---------------- sequential compose of (m,n) boundary states across 64 chunks (tiny)
__global__ __launch_bounds__(256) void chunk_compose(
    const float* __restrict__ Csum, const float* __restrict__ Mu, const float* __restrict__ Bn,
    float* __restrict__ mIn, float* __restrict__ nIn, float* __restrict__ Th,
    float* __restrict__ Dd)
{
    const int b = blockIdx.x;
    const int j = threadIdx.x;
    float m = 0.f, n = 0.f;
    for (int c = 0; c < NCH; ++c) {
        size_t o = ((size_t)b*NCH + c)*DMODEL + j;
        mIn[o] = m; nIn[o] = n;
        float cs = Csum[o], mu = Mu[o], bn = Bn[o];
        float th = fmaxf(m, mu);
        Th[o] = th;
        float d = __expf(m - th);
        Dd[o] = d;
        n = d*n + __expf(mu - th)*bn;
        m = cs + th;
    }
}

// ---------------- Delta-M per chunk: DM[b,c] = Bhat^T K  (256x256, MFMA) -> bf16
__global__ __launch_bounds__(256) void s2_dm(
    const float* __restrict__ kP, const float* __restrict__ vP,
    const float* __restrict__ liP, const float* __restrict__ lfP,
    const float* __restrict__ Th, bf16* __restrict__ DM)
{
    __shared__ bf16 BTh[DMODEL][40], BTl[DMODEL][40];
    __shared__ bf16 KTh[DMODEL][40], KTl[DMODEL][40];
    const int tid = threadIdx.x;
    const int w = tid >> 6, l = tid & 63;
    const int b = blockIdx.x >> 6, c = blockIdx.x & 63;
    const size_t pb = ((size_t)b*T_LEN + (size_t)c*CH_L)*DMODEL;

    {
        const float thL = Th[((size_t)b*NCH + c)*DMODEL + tid];
        float C = 0.f;
        #pragma unroll
        for (int s = 0; s < CH_L; ++s) {
            size_t o = pb + (size_t)s*DMODEL + tid;
            float lf = lfP[o], li = liP[o], vv = vP[o], kv = kP[o];
            C += lf;
            float bv = __expf(li - C - thL) * vv;
            bf16 h, lo; split_bf16(bv, h, lo);
            BTh[tid][s] = h; BTl[tid][s] = lo;
            bf16 kh, kl; split_bf16(kv, kh, kl);
            KTh[tid][s] = kh; KTl[tid][s] = kl;
        }
    }
    __syncthreads();

    const int lr = l & 15, lk = l >> 4;
    bf16x8 Ah[4], Al[4];
    #pragma unroll
    for (int it = 0; it < 4; ++it) {
        int row = w*64 + it*16 + lr;
        Ah[it] = *(const bf16x8*)&BTh[row][lk*8];
        Al[it] = *(const bf16x8*)&BTl[row][lk*8];
    }
    bf16* DMc = DM + (size_t)((size_t)b*NCH + c)*MSLOT;
    #pragma unroll
    for (int jt = 0; jt < 16; ++jt) {
        int jcol = jt*16 + lr;
        bf16x8 bh = *(const bf16x8*)&KTh[jcol][lk*8];
        bf16x8 bl = *(const bf16x8*)&KTl[jcol][lk*8];
        #pragma unroll
        for (int it = 0; it < 4; ++it) {
            f32x4 a = {0.f,0.f,0.f,0.f};
            a = MFMA(Ah[it], bh, a);
            a = MFMA(Al[it], bh, a);
            a = MFMA(Ah[it], bl, a);
            #pragma unroll
            for (int r = 0; r < 4; ++r)
                DMc[(size_t)(w*64 + it*16 + lk*4 + r)*DMODEL + jcol] = (bf16)a[r];
        }
    }
}

// ---------------- compose M across chunks per (b,i,j); bf16 in/out, fp32 accumulate
__global__ __launch_bounds__(256) void s3_compose(
    const float* __restrict__ Dd, bf16* __restrict__ DM)
{
    const int b = blockIdx.x >> 8, i = blockIdx.x & 255;
    const int j = threadIdx.x;
    float acc = 0.f;
    const size_t base = ((size_t)b*NCH)*MSLOT + (size_t)i*DMODEL + j;
    for (int c = 0; c < NCH; ++c) {
        size_t a = base + (size_t)c*MSLOT;
        float dm = (float)DM[a];
        if (c > 0) DM[a] = (bf16)acc;
        float d = Dd[((size_t)b*NCH + c)*DMODEL + i];
        acc = d*acc + dm;
    }
}

// ---------------- per-chunk output + fused RMSNorm:
// H = F1*(Q Mprev^T) + Bt*(Gm^T Bhat); h = sigma(o)*H/denom; out = h/rms * scale
__global__ __launch_bounds__(256) void s4_chunk(
    const float* __restrict__ qP, const float* __restrict__ kP, const float* __restrict__ vP,
    const float* __restrict__ liP, const float* __restrict__ lfP, const float* __restrict__ soP,
    const float* __restrict__ mIn, const float* __restrict__ nIn, const float* __restrict__ Th,
    const bf16* __restrict__ DM, const float* __restrict__ norm_scale,
    float* __restrict__ out)
{
    __shared__ float Kf[CH_L][268];
    __shared__ float Qf[CH_L][268];       // aliased as Hout in the epilogue
    __shared__ float Pbuf[CH_L][260];     // aliased as packed scales
    __shared__ bf16 BTh[DMODEL][40];
    __shared__ float GT[CH_L][44];
    __shared__ float denoms[CH_L];

    const int tid = threadIdx.x;
    const int w = tid >> 6, l = tid & 63;
    const int b = blockIdx.x >> 6;
    const int c = blockIdx.x & 63;
    const size_t pb = ((size_t)b*T_LEN + (size_t)c*CH_L)*DMODEL;

    // phase 0: stage K,Q fp32 rows into LDS (completes under phase 1)
    #pragma unroll
    for (int r8 = 0; r8 < 8; ++r8) {
        int row = w*8 + r8;
        GLD16(kP + pb + (size_t)row*DMODEL + l*4, &Kf[row][l*4]);
        GLD16(qP + pb + (size_t)row*DMODEL + l*4, &Qf[row][l*4]);
    }

    // phase 1: per-dim recurrences (thread = dim)
    const int i = tid;
    const size_t cbx = ((size_t)b*NCH + c)*DMODEL + i;
    const float thL = Th[cbx];
    const float mI = mIn[cbx];
    float th_arr[CH_L];
    {
        float C = 0.f, mu = -3e38f, n = nIn[cbx], thp = mI;
        #pragma unroll
        for (int t = 0; t < CH_L; ++t) {
            size_t o = pb + (size_t)t*DMODEL + i;
            float lf = lfP[o], li = liP[o], kv = kP[o], qv = qP[o], vv = vP[o];
            C += lf;
            float vlc = li - C;
            mu = fmaxf(mu, vlc);
            float tht = fmaxf(mI, mu);
            th_arr[t] = tht;
            float f = __expf(thp - tht);
            float iv = __expf(vlc - tht);
            n = f*n + iv*kv;
            thp = tht;
            Pbuf[t][i] = n * qv;
            BTh[i][t] = (bf16)(__expf(vlc - thL) * vv);
        }
    }
    __syncthreads();

    // phase 2: denominators
    #pragma unroll
    for (int r = 0; r < 8; ++r) {
        int t = w*8 + r;
        f32x4 pv = *(const f32x4*)&Pbuf[t][l*4];
        float s = pv[0]+pv[1]+pv[2]+pv[3];
        #pragma unroll
        for (int sh = 32; sh; sh >>= 1) s += __shfl_xor(s, sh);
        if (l == 0) denoms[t] = fmaxf(fabsf(s), 1e-6f);
    }
    __syncthreads();

    // phase 3a: packed scales (F1, Bt) -> alias over Pbuf
    u32 (*scl)[260] = (u32(*)[260])Pbuf;
    #pragma unroll
    for (int t = 0; t < CH_L; ++t) {
        float F1 = __expf(mI - th_arr[t]);
        float Bt = __expf(thL - th_arr[t]);
        union { bf16 b; u16 u; } a1, a2; a1.b = (bf16)F1; a2.b = (bf16)Bt;
        scl[t][i] = (u32)a1.u | ((u32)a2.u << 16);
    }
    // phase 3b: G = K Q^T, one 16x16 tile per wave, masked write transposed
    {
        const int srow = (w & 1)*16, tcol = (w >> 1)*16;
        const int lr = l & 15, lk2 = l >> 4;
        f32x4 g = {0.f,0.f,0.f,0.f};
        #pragma unroll
        for (int ks = 0; ks < 8; ++ks) {
            bf16x8 ah, al, bh, bl;
            split8(&Kf[srow + lr][ks*32 + lk2*8], ah, al);
            split8(&Qf[tcol + lr][ks*32 + lk2*8], bh, bl);
            g = MFMA(ah, bh, g);
            g = MFMA(al, bh, g);
            g = MFMA(ah, bl, g);
        }
        #pragma unroll
        for (int r = 0; r < 4; ++r) {
            int s = srow + lk2*4 + r, t = tcol + lr;
            GT[t][s] = (s <= t) ? g[r] : 0.f;
        }
    }
    __syncthreads();

    // phase 4: output GEMMs. wave -> (t-half tt, 8 i-tiles)
    const int tt = w & 1;
    const int lr = l & 15, lk2 = l >> 4;
    const int trow = tt*16 + lr;
    f32x4 acc_a[8], acc_b[8];

    {   // intra: Gm^T Bhat  (K-dim = 32 = chunk)
        bf16x8 gh, gl;
        split8(&GT[trow][lk2*8], gh, gl);
        #pragma unroll
        for (int it = 0; it < 8; ++it) {
            int irow = ((w>>1)*8 + it)*16 + lr;
            bf16x8 bb = *(const bf16x8*)&BTh[irow][lk2*8];
            f32x4 a = {0.f,0.f,0.f,0.f};
            a = MFMA(gh, bb, a);
            a = MFMA(gl, bb, a);
            acc_a[it] = a;
        }
    }
    #pragma unroll
    for (int it = 0; it < 8; ++it) acc_b[it] = (f32x4){0.f,0.f,0.f,0.f};
    if (c > 0) {   // inter: Q Mprev^T, Mprev streamed bf16 from global
        const u16* Mbase = (const u16*)DM + (size_t)((size_t)b*NCH + c)*MSLOT;
        #pragma unroll
        for (int ks = 0; ks < 8; ++ks) {
            bf16x8 qh, ql;
            split8(&Qf[trow][ks*32 + lk2*8], qh, ql);
            #pragma unroll
            for (int it = 0; it < 8; ++it) {
                int irow = ((w>>1)*8 + it)*16 + lr;
                union { u16x8 u; bf16x8 h; } M8;
                M8.u = *(const u16x8*)(Mbase + (size_t)irow*DMODEL + ks*32 + lk2*8);
                f32x4 a = acc_b[it];
                a = MFMA(qh, M8.h, a);
                a = MFMA(ql, M8.h, a);
                acc_b[it] = a;
            }
        }
    }
    // epilogue part 1: combine into pre-norm h, park in LDS (alias Qf after all reads done)
    __syncthreads();
    float* Hout = &Qf[0][0];             // [32][268]
    #pragma unroll
    for (int it = 0; it < 8; ++it) {
        int icol = ((w>>1)*8 + it)*16 + lr;
        #pragma unroll
        for (int r = 0; r < 4; ++r) {
            int t = tt*16 + lk2*4 + r;
            u32 sc = scl[t][icol];
            float h = bflo(sc)*acc_b[it][r] + bfhi(sc)*acc_a[it][r];
            size_t o = pb + (size_t)t*DMODEL + icol;
            Hout[t*268 + icol] = soP[o] * h / denoms[t];
        }
    }
    __syncthreads();
    // epilogue part 2: fused RMSNorm (wave w owns rows w*8..w*8+7), coalesced stores
    #pragma unroll
    for (int r = 0; r < 8; ++r) {
        int t = w*8 + r;
        f32x4 hv = *(const f32x4*)&Hout[t*268 + l*4];
        float ss = hv[0]*hv[0] + hv[1]*hv[1] + hv[2]*hv[2] + hv[3]*hv[3];
        #pragma unroll
        for (int sh = 32; sh; sh >>= 1) ss += __shfl_xor(ss, sh);
        float rinv = rsqrtf(ss * (1.0f/256.0f) + 1e-8f);
        f32x4 ns = *(const f32x4*)(norm_scale + l*4);
        f32x4 o4;
        #pragma unroll
        for (int e = 0; e < 4; ++e) o4[e] = hv[e] * rinv * ns[e];
        *(f32x4*)(out + pb + (size_t)t*DMODEL + l*4) = o4;
    }
}

extern "C" void kernel_launch(void* const* d_in, const int* in_sizes, int n_in,
                              void* d_out, int out_size, void* d_ws, size_t ws_size,
                              hipStream_t stream) {
    const float* x          = (const float*)d_in[0];
    const float* Wq         = (const float*)d_in[1];
    const float* bq         = (const float*)d_in[2];
    const float* Wk         = (const float*)d_in[3];
    const float* bk         = (const float*)d_in[4];
    const float* Wv         = (const float*)d_in[5];
    const float* bv         = (const float*)d_in[6];
    const float* Wg         = (const float*)d_in[7];
    const float* bg         = (const float*)d_in[8];
    const float* input_bias = (const float*)d_in[9];
    const float* norm_scale = (const float*)d_in[10];
    float* out = (float*)d_out;

    float* qP   = (float*)d_ws;
    float* kP   = qP  + PLANE;
    float* vP   = kP  + PLANE;
    float* liP  = vP  + PLANE;
    float* lfP  = liP + PLANE;
    float* soP  = lfP + PLANE;
    float* Csum = soP + PLANE;
    float* Mu   = Csum + SUMSZ;
    float* Bn   = Mu   + SUMSZ;
    float* mIn  = Bn   + SUMSZ;
    float* nIn  = mIn  + SUMSZ;
    float* Th   = nIn  + SUMSZ;
    float* Dd   = Th   + SUMSZ;
    bf16*  DM   = (bf16*)(Dd + SUMSZ);                // 4*64*65536 bf16 = 32 MiB
    bf16*  WhT  = DM + (size_t)BATCH*NCH*MSLOT;
    bf16*  WlT  = WhT + 1536*256;
    bf16*  xh   = WlT + 1536*256;
    bf16*  xl   = xh + PLANE;

    pack_w<<<dim3(96), dim3(256), 0, stream>>>(Wq, Wk, Wv, Wg, WhT, WlT);
    split_x<<<dim3(1024), dim3(256), 0, stream>>>(x, xh, xl);
    proj_gemm<<<dim3(64, 12), dim3(256), 0, stream>>>(xh, xl, WhT, WlT, bq, bk, bv, bg, input_bias,
                                                      qP, kP, vP, liP, lfP, soP);
    chunk_summary<<<dim3(BATCH*NCH), dim3(256), 0, stream>>>(lfP, liP, kP, Csum, Mu, Bn);
    chunk_compose<<<dim3(BATCH), dim3(256), 0, stream>>>(Csum, Mu, Bn, mIn, nIn, Th, Dd);
    s2_dm<<<dim3(BATCH*NCH), dim3(256), 0, stream>>>(kP, vP, liP, lfP, Th, DM);
    s3_compose<<<dim3(BATCH*256), dim3(256), 0, stream>>>(Dd, DM);
    s4_chunk<<<dim3(BATCH*NCH), dim3(256), 0, stream>>>(qP, kP, vP, liP, lfP, soP,
                                                        mIn, nIn, Th, DM, norm_scale, out);
}